// Round 5
// baseline (111.363 us; speedup 1.0000x reference)
//
#include <hip/hip_runtime.h>
#include <cstdint>
#include <cstddef>

typedef float f32x4  __attribute__((ext_vector_type(4)));
typedef short bf16x8 __attribute__((ext_vector_type(8)));
typedef int   i32x4  __attribute__((ext_vector_type(4)));

#define LN_EPS 1e-5f

static __device__ __forceinline__ unsigned short f2bf(float f) {
    unsigned int u = __float_as_uint(f);
    u += 0x7fffu + ((u >> 16) & 1u);          // RNE
    return (unsigned short)(u >> 16);
}
static __device__ __forceinline__ float bf2f(unsigned short h) {
    return __uint_as_float(((unsigned int)h) << 16);
}

// ---- prep: merge_w (192x384 f32) -> bf16 hi/lo pair in MFMA B-frag order ----
// index o = ((kk*12+nf)*64 + lane)*8 + j  ->  W[nf*16+(lane&15)][kk*32+(lane>>4)*8+j]
__global__ void prep_w_kernel(const float* __restrict__ W,
                              unsigned short* __restrict__ wsh,
                              unsigned short* __restrict__ wsl) {
    int o = blockIdx.x * 256 + threadIdx.x;
    if (o >= 192 * 384) return;
    int j    = o & 7;
    int lane = (o >> 3) & 63;
    int t    = o >> 9;
    int nf   = t % 12;
    int kk   = t / 12;
    int n = nf * 16 + (lane & 15);
    int k = kk * 32 + (lane >> 4) * 8 + j;
    float w = W[n * 384 + k];
    unsigned short hi = f2bf(w);
    wsh[o] = hi;
    wsl[o] = f2bf(w - bf2f(hi));              // exact residual, then RNE
}

template <bool USE_WS>
__global__ __launch_bounds__(256, 6)
void fused_kernel(const float* __restrict__ x,
                  const unsigned short* __restrict__ wsh,
                  const unsigned short* __restrict__ wsl,
                  const float* __restrict__ Wf,
                  const float* __restrict__ mw, const float* __restrict__ mb,
                  const float* __restrict__ vw, const float* __restrict__ vb,
                  const float* __restrict__ aw, const float* __restrict__ ab,
                  const float* __restrict__ fw, const float* __restrict__ fb,
                  float* __restrict__ out) {
    // [0,12288): A-hi bf16 16x384 swizzled ; [12288,24576): A-lo ;
    // xs f32 16x196 (12544 B) overlays at 0 after the MFMA phase.
    __shared__ __align__(16) unsigned char lds[24576];

    const int tid = threadIdx.x;
    const int r   = tid >> 4;        // row 0..15
    const int u   = tid & 15;        // 16 threads/row
    const int q   = u >> 2;          // patch chunk 0..3
    const int uu  = u & 3;           // quarter of 96-chunk (24 elems)

    const int wv = tid >> 6;
    const int l  = tid & 63;
    const int g  = l >> 4;
    const int cl = l & 15;

    // ---------------- stage: gather + LN(merge) -> bf16 hi/lo LDS tiles ----------------
    {
        const int R   = blockIdx.x * 16 + r;
        const int b   = R / 12544;
        const int rem = R - b * 12544;
        const int h2  = rem / 112;
        const int w2  = rem - h2 * 112;
        const int h   = 2 * h2 + (q & 1);       // x0,x1,x2,x3 concat order
        const int w   = 2 * w2 + (q >> 1);
        const f32x4* src = (const f32x4*)(x + (((size_t)b * 224 + h) * 224 + w) * 96 + uu * 24);
        f32x4 v[6];
        #pragma unroll
        for (int i = 0; i < 6; i++) v[i] = src[i];

        float s = 0.f;
        #pragma unroll
        for (int i = 0; i < 6; i++) {
            #pragma unroll
            for (int e = 0; e < 4; e++) s += v[i][e];
        }
        s += __shfl_xor(s, 1); s += __shfl_xor(s, 2);
        s += __shfl_xor(s, 4); s += __shfl_xor(s, 8);
        const float mu = s * (1.f / 384.f);
        float sd = 0.f;
        #pragma unroll
        for (int i = 0; i < 6; i++) {
            #pragma unroll
            for (int e = 0; e < 4; e++) { float d = v[i][e] - mu; sd += d * d; }
        }
        sd += __shfl_xor(sd, 1); sd += __shfl_xor(sd, 2);
        sd += __shfl_xor(sd, 4); sd += __shfl_xor(sd, 8);
        const float rs = rsqrtf(sd * (1.f / 384.f) + LN_EPS);   // two-pass var (matches ref)

        const f32x4* mwv = (const f32x4*)(mw + q * 96 + uu * 24);
        const f32x4* mbv = (const f32x4*)(mb + q * 96 + uu * 24);
        #pragma unroll
        for (int c = 0; c < 3; c++) {
            union { unsigned short u16[8]; i32x4 v4; } ph, pl;
            #pragma unroll
            for (int half = 0; half < 2; half++) {
                const int i = 2 * c + half;
                f32x4 w4 = mwv[i], b4 = mbv[i];
                #pragma unroll
                for (int e = 0; e < 4; e++) {
                    float a = (v[i][e] - mu) * rs * w4[e] + b4[e];
                    unsigned short hi = f2bf(a);
                    ph.u16[4 * half + e] = hi;
                    pl.u16[4 * half + e] = f2bf(a - bf2f(hi));
                }
            }
            const int boff = (u * 48 + c * 16) ^ ((r & 7) << 4);   // XOR swizzle (G4)
            *(i32x4*)(&lds[r * 768 + boff])         = ph.v4;
            *(i32x4*)(&lds[12288 + r * 768 + boff]) = pl.v4;
        }
    }
    __syncthreads();

    // ---------------- MFMA: wave wv -> rows 0..15 x cols [48wv,48wv+48), 3-pass split ----
    f32x4 acc[3];
    #pragma unroll
    for (int t = 0; t < 3; t++) acc[t] = (f32x4){0.f, 0.f, 0.f, 0.f};

    #pragma unroll
    for (int kk = 0; kk < 12; kk++) {
        bf16x8 bh[3], bl[3];
        if (USE_WS) {
            const bf16x8* bph = (const bf16x8*)wsh + ((kk * 12 + 3 * wv) * 64 + l);
            const bf16x8* bpl = (const bf16x8*)wsl + ((kk * 12 + 3 * wv) * 64 + l);
            bh[0] = bph[0]; bh[1] = bph[64]; bh[2] = bph[128];
            bl[0] = bpl[0]; bl[1] = bpl[64]; bl[2] = bpl[128];
        } else {
            #pragma unroll
            for (int t = 0; t < 3; t++) {
                const int n = (3 * wv + t) * 16 + cl;
                const float* wp = Wf + n * 384 + kk * 32 + g * 8;
                f32x4 lo = *(const f32x4*)wp;
                f32x4 hi4 = *(const f32x4*)(wp + 4);
                bf16x8 hbb, lbb;
                #pragma unroll
                for (int e = 0; e < 4; e++) {
                    unsigned short h0 = f2bf(lo[e]), h1 = f2bf(hi4[e]);
                    hbb[e] = (short)h0; hbb[4 + e] = (short)h1;
                    lbb[e] = (short)f2bf(lo[e] - bf2f(h0));
                    lbb[4 + e] = (short)f2bf(hi4[e] - bf2f(h1));
                }
                bh[t] = hbb; bl[t] = lbb;
            }
        }
        const int boff = (kk * 64 + g * 16) ^ ((cl & 7) << 4);
        bf16x8 afh = *(const bf16x8*)(&lds[cl * 768 + boff]);
        bf16x8 afl = *(const bf16x8*)(&lds[12288 + cl * 768 + boff]);
        #pragma unroll
        for (int t = 0; t < 3; t++) {
            acc[t] = __builtin_amdgcn_mfma_f32_16x16x32_bf16(afh, bh[t], acc[t], 0, 0, 0);
            acc[t] = __builtin_amdgcn_mfma_f32_16x16x32_bf16(afl, bh[t], acc[t], 0, 0, 0);
            acc[t] = __builtin_amdgcn_mfma_f32_16x16x32_bf16(afh, bl[t], acc[t], 0, 0, 0);
        }
    }
    __syncthreads();   // all A-reads done; reuse LDS for xs

    // ---------------- xs -> LDS f32 [16][196] ----------------
    {
        float* xsl = (float*)lds;
        #pragma unroll
        for (int t = 0; t < 3; t++) {
            const int col = 48 * wv + 16 * t + cl;   // D: col=lane&15, row=4*(lane>>4)+reg
            #pragma unroll
            for (int rg = 0; rg < 4; rg++) {
                const int row = 4 * g + rg;
                xsl[row * 196 + col] = acc[t][rg];
            }
        }
    }
    __syncthreads();

    // ---------------- epilogue: xv = xs + LN(xs); xa = LN(xv); out = LN(xa) ----------------
    {
        const float* rowp = (const float*)lds + r * 196 + u * 12;
        float vv[12];
        #pragma unroll
        for (int i = 0; i < 3; i++) {
            f32x4 t4 = *(const f32x4*)(rowp + 4 * i);
            #pragma unroll
            for (int e = 0; e < 4; e++) vv[4 * i + e] = t4[e];
        }
        float s1 = 0.f;
        #pragma unroll
        for (int i = 0; i < 12; i++) s1 += vv[i];
        s1 += __shfl_xor(s1, 1); s1 += __shfl_xor(s1, 2);
        s1 += __shfl_xor(s1, 4); s1 += __shfl_xor(s1, 8);
        const float mu1 = s1 * (1.f / 192.f);
        float d1 = 0.f;
        #pragma unroll
        for (int i = 0; i < 12; i++) { float d = vv[i] - mu1; d1 += d * d; }
        d1 += __shfl_xor(d1, 1); d1 += __shfl_xor(d1, 2);
        d1 += __shfl_xor(d1, 4); d1 += __shfl_xor(d1, 8);
        const float r1 = rsqrtf(d1 * (1.f / 192.f) + LN_EPS);

        const f32x4* vwv = (const f32x4*)(vw + u * 12);
        const f32x4* vbv = (const f32x4*)(vb + u * 12);
        float s2 = 0.f;
        #pragma unroll
        for (int i = 0; i < 3; i++) {
            f32x4 w4 = vwv[i], b4 = vbv[i];
            #pragma unroll
            for (int e = 0; e < 4; e++) {
                float xs0 = vv[4 * i + e];
                float xv0 = xs0 + (xs0 - mu1) * r1 * w4[e] + b4[e];
                vv[4 * i + e] = xv0;
                s2 += xv0;
            }
        }
        s2 += __shfl_xor(s2, 1); s2 += __shfl_xor(s2, 2);
        s2 += __shfl_xor(s2, 4); s2 += __shfl_xor(s2, 8);
        const float mu2 = s2 * (1.f / 192.f);
        float d2 = 0.f;
        #pragma unroll
        for (int i = 0; i < 12; i++) { float d = vv[i] - mu2; d2 += d * d; }
        d2 += __shfl_xor(d2, 1); d2 += __shfl_xor(d2, 2);
        d2 += __shfl_xor(d2, 4); d2 += __shfl_xor(d2, 8);
        const float r2 = rsqrtf(d2 * (1.f / 192.f) + LN_EPS);

        const f32x4* awv = (const f32x4*)(aw + u * 12);
        const f32x4* abv = (const f32x4*)(ab + u * 12);
        float s3 = 0.f;
        #pragma unroll
        for (int i = 0; i < 3; i++) {
            f32x4 w4 = awv[i], b4 = abv[i];
            #pragma unroll
            for (int e = 0; e < 4; e++) {
                float xa0 = (vv[4 * i + e] - mu2) * r2 * w4[e] + b4[e];
                vv[4 * i + e] = xa0;
                s3 += xa0;
            }
        }
        s3 += __shfl_xor(s3, 1); s3 += __shfl_xor(s3, 2);
        s3 += __shfl_xor(s3, 4); s3 += __shfl_xor(s3, 8);
        const float mu3 = s3 * (1.f / 192.f);
        float d3 = 0.f;
        #pragma unroll
        for (int i = 0; i < 12; i++) { float d = vv[i] - mu3; d3 += d * d; }
        d3 += __shfl_xor(d3, 1); d3 += __shfl_xor(d3, 2);
        d3 += __shfl_xor(d3, 4); d3 += __shfl_xor(d3, 8);
        const float r3 = rsqrtf(d3 * (1.f / 192.f) + LN_EPS);

        const f32x4* fwv = (const f32x4*)(fw + u * 12);
        const f32x4* fbv = (const f32x4*)(fb + u * 12);
        float* op = out + (size_t)(blockIdx.x * 16 + r) * 192 + u * 12;
        #pragma unroll
        for (int i = 0; i < 3; i++) {
            f32x4 w4 = fwv[i], b4 = fbv[i];
            f32x4 o4;
            #pragma unroll
            for (int e = 0; e < 4; e++)
                o4[e] = (vv[4 * i + e] - mu3) * r3 * w4[e] + b4[e];
            *(f32x4*)(op + 4 * i) = o4;
        }
    }
}

extern "C" void kernel_launch(void* const* d_in, const int* in_sizes, int n_in,
                              void* d_out, int out_size, void* d_ws, size_t ws_size,
                              hipStream_t stream) {
    const float* x  = (const float*)d_in[0];
    /* d_in[1] saliency_map: dead code in reference */
    const float* W  = (const float*)d_in[2];
    const float* mw = (const float*)d_in[3];
    const float* mb = (const float*)d_in[4];
    const float* vw = (const float*)d_in[5];
    const float* vb = (const float*)d_in[6];
    const float* aw = (const float*)d_in[7];
    const float* ab = (const float*)d_in[8];
    const float* fw = (const float*)d_in[9];
    const float* fb = (const float*)d_in[10];
    float* out = (float*)d_out;

    const int rows   = 8 * 112 * 112;     // 100352
    const int blocks = rows / 16;         // 6272

    unsigned short* wsh = (unsigned short*)d_ws;
    unsigned short* wsl = wsh + 192 * 384;

    if (ws_size >= (size_t)(2 * 192 * 384 * 2)) {
        prep_w_kernel<<<288, 256, 0, stream>>>(W, wsh, wsl);
        fused_kernel<true><<<blocks, 256, 0, stream>>>(x, wsh, wsl, W, mw, mb, vw, vb,
                                                       aw, ab, fw, fb, out);
    } else {
        fused_kernel<false><<<blocks, 256, 0, stream>>>(x, wsh, wsl, W, mw, mb, vw, vb,
                                                        aw, ab, fw, fb, out);
    }
}

// Round 6
// 89.314 us; speedup vs baseline: 1.2469x; 1.2469x over previous
//
#include <hip/hip_runtime.h>
#include <cstdint>
#include <cstddef>

typedef float f32x4  __attribute__((ext_vector_type(4)));
typedef short bf16x8 __attribute__((ext_vector_type(8)));
typedef int   i32x4  __attribute__((ext_vector_type(4)));

#define LN_EPS 1e-5f

static __device__ __forceinline__ unsigned short f2bf(float f) {
    unsigned int u = __float_as_uint(f);
    u += 0x7fffu + ((u >> 16) & 1u);          // RNE
    return (unsigned short)(u >> 16);
}
static __device__ __forceinline__ float bf2f(unsigned short h) {
    return __uint_as_float(((unsigned int)h) << 16);
}

// ---- prep: merge_w (192x384 f32) -> bf16 (hi) in MFMA B-frag order ----
// index o = ((kk*12+nf)*64 + lane)*8 + j  ->  W[nf*16+(lane&15)][kk*32+(lane>>4)*8+j]
__global__ void prep_w_kernel(const float* __restrict__ W,
                              unsigned short* __restrict__ wsh) {
    int o = blockIdx.x * 256 + threadIdx.x;
    if (o >= 192 * 384) return;
    int j    = o & 7;
    int lane = (o >> 3) & 63;
    int t    = o >> 9;
    int nf   = t % 12;
    int kk   = t / 12;
    int n = nf * 16 + (lane & 15);
    int k = kk * 32 + (lane >> 4) * 8 + j;
    wsh[o] = f2bf(W[n * 384 + k]);
}

template <bool USE_WS>
__global__ __launch_bounds__(256, 3)
void fused_kernel(const float* __restrict__ x,
                  const unsigned short* __restrict__ wsh,
                  const float* __restrict__ Wf,
                  const float* __restrict__ mw, const float* __restrict__ mb,
                  const float* __restrict__ vw, const float* __restrict__ vb,
                  const float* __restrict__ aw, const float* __restrict__ ab,
                  const float* __restrict__ fw, const float* __restrict__ fb,
                  float* __restrict__ out) {
    // [0,24576): A-hi bf16 32x384 swizzled ; [24576,49152): A-lo ; xs f32 32x196 overlays at 0
    __shared__ __align__(16) unsigned char lds[49152];

    const int tid = threadIdx.x;
    const int r   = tid >> 3;        // row 0..31
    const int u   = tid & 7;         // 8 threads/row
    const int q   = u >> 1;          // patch chunk 0..3
    const int hh  = u & 1;           // half of 96-chunk

    const int wv = tid >> 6;
    const int l  = tid & 63;
    const int g  = l >> 4;
    const int cl = l & 15;

    // ---------------- stage: gather + LN(merge) -> bf16 hi/lo LDS tiles ----------------
    {
        const int R   = blockIdx.x * 32 + r;
        const int b   = R / 12544;
        const int rem = R - b * 12544;
        const int h2  = rem / 112;
        const int w2  = rem - h2 * 112;
        const int h   = 2 * h2 + (q & 1);       // x0,x1,x2,x3 concat order
        const int w   = 2 * w2 + (q >> 1);
        const f32x4* src = (const f32x4*)(x + (((size_t)b * 224 + h) * 224 + w) * 96 + hh * 48);
        f32x4 v[12];
        #pragma unroll
        for (int i = 0; i < 12; i++) v[i] = src[i];

        float s = 0.f;
        #pragma unroll
        for (int i = 0; i < 12; i++) {
            #pragma unroll
            for (int e = 0; e < 4; e++) s += v[i][e];
        }
        s += __shfl_xor(s, 1); s += __shfl_xor(s, 2); s += __shfl_xor(s, 4);
        const float mu = s * (1.f / 384.f);
        float sd = 0.f;
        #pragma unroll
        for (int i = 0; i < 12; i++) {
            #pragma unroll
            for (int e = 0; e < 4; e++) { float d = v[i][e] - mu; sd += d * d; }
        }
        sd += __shfl_xor(sd, 1); sd += __shfl_xor(sd, 2); sd += __shfl_xor(sd, 4);
        const float rs = rsqrtf(sd * (1.f / 384.f) + LN_EPS);   // two-pass var (matches ref)

        const f32x4* mwv = (const f32x4*)(mw + q * 96 + hh * 48);
        const f32x4* mbv = (const f32x4*)(mb + q * 96 + hh * 48);
        #pragma unroll
        for (int p = 0; p < 6; p++) {
            union { unsigned short u16[8]; i32x4 v4; } ph, pl;
            #pragma unroll
            for (int half = 0; half < 2; half++) {
                const int i = 2 * p + half;
                f32x4 w4 = mwv[i], b4 = mbv[i];
                #pragma unroll
                for (int e = 0; e < 4; e++) {
                    float a = (v[i][e] - mu) * rs * w4[e] + b4[e];
                    unsigned short hi = f2bf(a);
                    ph.u16[4 * half + e] = hi;
                    pl.u16[4 * half + e] = f2bf(a - bf2f(hi));
                }
            }
            const int slot = 6 * u + p;                         // elements 8*slot..+7
            const int boff = (slot * 16) ^ ((r & 7) << 4);      // XOR swizzle
            *(i32x4*)(&lds[r * 768 + boff])         = ph.v4;
            *(i32x4*)(&lds[24576 + r * 768 + boff]) = pl.v4;
        }
    }
    __syncthreads();

    // ---------------- MFMA: wave wv -> rows 0..31 x cols [48wv,48wv+48), 2-pass split ----
    f32x4 acc[2][3];
    #pragma unroll
    for (int mf = 0; mf < 2; mf++)
        #pragma unroll
        for (int t = 0; t < 3; t++) acc[mf][t] = (f32x4){0.f, 0.f, 0.f, 0.f};

    #pragma unroll
    for (int kk = 0; kk < 12; kk++) {
        bf16x8 bh[3];
        if (USE_WS) {
            const bf16x8* bph = (const bf16x8*)wsh + ((kk * 12 + 3 * wv) * 64 + l);
            bh[0] = bph[0]; bh[1] = bph[64]; bh[2] = bph[128];
        } else {
            #pragma unroll
            for (int t = 0; t < 3; t++) {
                const int n = (3 * wv + t) * 16 + cl;
                const float* wp = Wf + n * 384 + kk * 32 + g * 8;
                f32x4 lo = *(const f32x4*)wp;
                f32x4 hi4 = *(const f32x4*)(wp + 4);
                bf16x8 hbb;
                #pragma unroll
                for (int e = 0; e < 4; e++) {
                    hbb[e] = (short)f2bf(lo[e]); hbb[4 + e] = (short)f2bf(hi4[e]);
                }
                bh[t] = hbb;
            }
        }
        #pragma unroll
        for (int mf = 0; mf < 2; mf++) {
            const int row  = 16 * mf + cl;
            const int boff = (kk * 64 + g * 16) ^ ((row & 7) << 4);
            bf16x8 afh = *(const bf16x8*)(&lds[row * 768 + boff]);
            bf16x8 afl = *(const bf16x8*)(&lds[24576 + row * 768 + boff]);
            #pragma unroll
            for (int t = 0; t < 3; t++) {
                acc[mf][t] = __builtin_amdgcn_mfma_f32_16x16x32_bf16(afh, bh[t], acc[mf][t], 0, 0, 0);
                acc[mf][t] = __builtin_amdgcn_mfma_f32_16x16x32_bf16(afl, bh[t], acc[mf][t], 0, 0, 0);
            }
        }
    }
    __syncthreads();   // all A-reads done; reuse LDS for xs

    // ---------------- xs -> LDS f32 [32][196] ----------------
    {
        float* xsl = (float*)lds;
        #pragma unroll
        for (int mf = 0; mf < 2; mf++)
            #pragma unroll
            for (int t = 0; t < 3; t++) {
                const int col = 48 * wv + 16 * t + cl;   // D: col=lane&15, row=4*(lane>>4)+reg
                #pragma unroll
                for (int rg = 0; rg < 4; rg++) {
                    const int row = 16 * mf + 4 * g + rg;
                    xsl[row * 196 + col] = acc[mf][t][rg];
                }
            }
    }
    __syncthreads();

    // ---------------- epilogue: xv = xs + LN(xs); xa = LN(xv); out = LN(xa) ----------------
    {
        const float* rowp = (const float*)lds + r * 196 + u * 24;
        float vv[24];
        #pragma unroll
        for (int i = 0; i < 6; i++) {
            f32x4 t4 = *(const f32x4*)(rowp + 4 * i);
            #pragma unroll
            for (int e = 0; e < 4; e++) vv[4 * i + e] = t4[e];
        }
        float s1 = 0.f;
        #pragma unroll
        for (int i = 0; i < 24; i++) s1 += vv[i];
        s1 += __shfl_xor(s1, 1); s1 += __shfl_xor(s1, 2); s1 += __shfl_xor(s1, 4);
        const float mu1 = s1 * (1.f / 192.f);
        float d1 = 0.f;
        #pragma unroll
        for (int i = 0; i < 24; i++) { float d = vv[i] - mu1; d1 += d * d; }
        d1 += __shfl_xor(d1, 1); d1 += __shfl_xor(d1, 2); d1 += __shfl_xor(d1, 4);
        const float r1 = rsqrtf(d1 * (1.f / 192.f) + LN_EPS);

        const f32x4* vwv = (const f32x4*)(vw + u * 24);
        const f32x4* vbv = (const f32x4*)(vb + u * 24);
        float s2 = 0.f;
        #pragma unroll
        for (int i = 0; i < 6; i++) {
            f32x4 w4 = vwv[i], b4 = vbv[i];
            #pragma unroll
            for (int e = 0; e < 4; e++) {
                float xs0 = vv[4 * i + e];
                float xv0 = xs0 + (xs0 - mu1) * r1 * w4[e] + b4[e];
                vv[4 * i + e] = xv0;
                s2 += xv0;
            }
        }
        s2 += __shfl_xor(s2, 1); s2 += __shfl_xor(s2, 2); s2 += __shfl_xor(s2, 4);
        const float mu2 = s2 * (1.f / 192.f);
        float d2 = 0.f;
        #pragma unroll
        for (int i = 0; i < 24; i++) { float d = vv[i] - mu2; d2 += d * d; }
        d2 += __shfl_xor(d2, 1); d2 += __shfl_xor(d2, 2); d2 += __shfl_xor(d2, 4);
        const float r2 = rsqrtf(d2 * (1.f / 192.f) + LN_EPS);

        const f32x4* awv = (const f32x4*)(aw + u * 24);
        const f32x4* abv = (const f32x4*)(ab + u * 24);
        float s3 = 0.f;
        #pragma unroll
        for (int i = 0; i < 6; i++) {
            f32x4 w4 = awv[i], b4 = abv[i];
            #pragma unroll
            for (int e = 0; e < 4; e++) {
                float xa0 = (vv[4 * i + e] - mu2) * r2 * w4[e] + b4[e];
                vv[4 * i + e] = xa0;
                s3 += xa0;
            }
        }
        s3 += __shfl_xor(s3, 1); s3 += __shfl_xor(s3, 2); s3 += __shfl_xor(s3, 4);
        const float mu3 = s3 * (1.f / 192.f);
        float d3 = 0.f;
        #pragma unroll
        for (int i = 0; i < 24; i++) { float d = vv[i] - mu3; d3 += d * d; }
        d3 += __shfl_xor(d3, 1); d3 += __shfl_xor(d3, 2); d3 += __shfl_xor(d3, 4);
        const float r3 = rsqrtf(d3 * (1.f / 192.f) + LN_EPS);

        const f32x4* fwv = (const f32x4*)(fw + u * 24);
        const f32x4* fbv = (const f32x4*)(fb + u * 24);
        float* op = out + (size_t)(blockIdx.x * 32 + r) * 192 + u * 24;
        #pragma unroll
        for (int i = 0; i < 6; i++) {
            f32x4 w4 = fwv[i], b4 = fbv[i];
            f32x4 o4;
            #pragma unroll
            for (int e = 0; e < 4; e++)
                o4[e] = (vv[4 * i + e] - mu3) * r3 * w4[e] + b4[e];
            *(f32x4*)(op + 4 * i) = o4;
        }
    }
}

extern "C" void kernel_launch(void* const* d_in, const int* in_sizes, int n_in,
                              void* d_out, int out_size, void* d_ws, size_t ws_size,
                              hipStream_t stream) {
    const float* x  = (const float*)d_in[0];
    /* d_in[1] saliency_map: dead code in reference */
    const float* W  = (const float*)d_in[2];
    const float* mw = (const float*)d_in[3];
    const float* mb = (const float*)d_in[4];
    const float* vw = (const float*)d_in[5];
    const float* vb = (const float*)d_in[6];
    const float* aw = (const float*)d_in[7];
    const float* ab = (const float*)d_in[8];
    const float* fw = (const float*)d_in[9];
    const float* fb = (const float*)d_in[10];
    float* out = (float*)d_out;

    const int rows   = 8 * 112 * 112;     // 100352
    const int blocks = rows / 32;         // 3136

    unsigned short* wsh = (unsigned short*)d_ws;

    if (ws_size >= (size_t)(192 * 384 * 2)) {
        prep_w_kernel<<<288, 256, 0, stream>>>(W, wsh);
        fused_kernel<true><<<blocks, 256, 0, stream>>>(x, wsh, W, mw, mb, vw, vb,
                                                       aw, ab, fw, fb, out);
    } else {
        fused_kernel<false><<<blocks, 256, 0, stream>>>(x, wsh, W, mw, mb, vw, vb,
                                                        aw, ab, fw, fb, out);
    }
}

// Round 7
// 87.704 us; speedup vs baseline: 1.2698x; 1.0184x over previous
//
#include <hip/hip_runtime.h>
#include <cstdint>
#include <cstddef>

typedef float f32x4  __attribute__((ext_vector_type(4)));
typedef short bf16x8 __attribute__((ext_vector_type(8)));
typedef int   i32x4  __attribute__((ext_vector_type(4)));

#define LN_EPS 1e-5f

static __device__ __forceinline__ unsigned short f2bf(float f) {
    unsigned int u = __float_as_uint(f);
    u += 0x7fffu + ((u >> 16) & 1u);          // RNE
    return (unsigned short)(u >> 16);
}
static __device__ __forceinline__ float bf2f(unsigned short h) {
    return __uint_as_float(((unsigned int)h) << 16);
}

// ---- prep: merge_w (192x384 f32) -> bf16 (hi) in MFMA B-frag order ----
// index o = ((kk*12+nf)*64 + lane)*8 + j  ->  W[nf*16+(lane&15)][kk*32+(lane>>4)*8+j]
__global__ void prep_w_kernel(const float* __restrict__ W,
                              unsigned short* __restrict__ wsh) {
    int o = blockIdx.x * 256 + threadIdx.x;
    if (o >= 192 * 384) return;
    int j    = o & 7;
    int lane = (o >> 3) & 63;
    int t    = o >> 9;
    int nf   = t % 12;
    int kk   = t / 12;
    int n = nf * 16 + (lane & 15);
    int k = kk * 32 + (lane >> 4) * 8 + j;
    wsh[o] = f2bf(W[n * 384 + k]);
}

template <bool USE_WS>
__global__ __launch_bounds__(256, 3)
void fused_kernel(const float* __restrict__ x,
                  const unsigned short* __restrict__ wsh,
                  const float* __restrict__ Wf,
                  const float* __restrict__ mw, const float* __restrict__ mb,
                  const float* __restrict__ vw, const float* __restrict__ vb,
                  const float* __restrict__ aw, const float* __restrict__ ab,
                  const float* __restrict__ fw, const float* __restrict__ fb,
                  float* __restrict__ out) {
    // [0,24576): A-hi bf16 32x384 swizzled ; [24576,49152): A-lo ; xs f32 32x196 overlays at 0
    __shared__ __align__(16) unsigned char lds[49152];

    const int tid = threadIdx.x;
    const int r   = tid >> 3;        // row 0..31
    const int u   = tid & 7;         // 8 threads/row
    const int q   = u >> 1;          // patch chunk 0..3
    const int hh  = u & 1;           // half of 96-chunk

    const int wv = tid >> 6;
    const int l  = tid & 63;
    const int g  = l >> 4;
    const int cl = l & 15;

    // ---------------- stage: gather + LN(merge) -> bf16 hi/lo LDS tiles ----------------
    {
        const int R   = blockIdx.x * 32 + r;
        const int b   = R / 12544;
        const int rem = R - b * 12544;
        const int h2  = rem / 112;
        const int w2  = rem - h2 * 112;
        const int h   = 2 * h2 + (q & 1);       // x0,x1,x2,x3 concat order
        const int w   = 2 * w2 + (q >> 1);
        const f32x4* src = (const f32x4*)(x + (((size_t)b * 224 + h) * 224 + w) * 96 + hh * 48);
        f32x4 v[12];
        #pragma unroll
        for (int i = 0; i < 12; i++) v[i] = src[i];

        float s = 0.f;
        #pragma unroll
        for (int i = 0; i < 12; i++) {
            #pragma unroll
            for (int e = 0; e < 4; e++) s += v[i][e];
        }
        s += __shfl_xor(s, 1); s += __shfl_xor(s, 2); s += __shfl_xor(s, 4);
        const float mu = s * (1.f / 384.f);
        float sd = 0.f;
        #pragma unroll
        for (int i = 0; i < 12; i++) {
            #pragma unroll
            for (int e = 0; e < 4; e++) { float d = v[i][e] - mu; sd += d * d; }
        }
        sd += __shfl_xor(sd, 1); sd += __shfl_xor(sd, 2); sd += __shfl_xor(sd, 4);
        const float rs = rsqrtf(sd * (1.f / 384.f) + LN_EPS);   // two-pass var (matches ref)

        const f32x4* mwv = (const f32x4*)(mw + q * 96 + hh * 48);
        const f32x4* mbv = (const f32x4*)(mb + q * 96 + hh * 48);
        #pragma unroll
        for (int p = 0; p < 6; p++) {
            union { unsigned short u16[8]; i32x4 v4; } ph, pl;
            #pragma unroll
            for (int half = 0; half < 2; half++) {
                const int i = 2 * p + half;
                f32x4 w4 = mwv[i], b4 = mbv[i];
                #pragma unroll
                for (int e = 0; e < 4; e++) {
                    float a = (v[i][e] - mu) * rs * w4[e] + b4[e];
                    unsigned short hi = f2bf(a);
                    ph.u16[4 * half + e] = hi;
                    pl.u16[4 * half + e] = f2bf(a - bf2f(hi));
                }
            }
            const int slot = 6 * u + p;                         // elements 8*slot..+7
            const int boff = (slot * 16) ^ ((r & 7) << 4);      // XOR swizzle
            *(i32x4*)(&lds[r * 768 + boff])         = ph.v4;
            *(i32x4*)(&lds[24576 + r * 768 + boff]) = pl.v4;
        }
    }
    __syncthreads();

    // ---------------- MFMA: wave wv -> rows 0..31 x cols [48wv,48wv+48), 2-pass split ----
    // W fragments hoisted to registers in two 18-frag bursts (kk 0..5, 6..11),
    // pinned with empty asm so the compiler cannot sink the loads back into the loop.
    f32x4 acc[2][3];
    #pragma unroll
    for (int mf = 0; mf < 2; mf++)
        #pragma unroll
        for (int t = 0; t < 3; t++) acc[mf][t] = (f32x4){0.f, 0.f, 0.f, 0.f};

    if (USE_WS) {
        #pragma unroll
        for (int half = 0; half < 2; half++) {
            bf16x8 B[6][3];
            // burst-issue 18 independent L2 loads
            #pragma unroll
            for (int kx = 0; kx < 6; kx++) {
                const int kk = 6 * half + kx;
                const bf16x8* bp = (const bf16x8*)wsh + ((kk * 12 + 3 * wv) * 64 + l);
                B[kx][0] = bp[0]; B[kx][1] = bp[64]; B[kx][2] = bp[128];
            }
            // pin: loads may not sink below this point
            #pragma unroll
            for (int kx = 0; kx < 6; kx++) {
                asm volatile("" : "+v"(B[kx][0]), "+v"(B[kx][1]), "+v"(B[kx][2]));
            }
            // pure LDS + MFMA compute for these 6 k-steps
            #pragma unroll
            for (int kx = 0; kx < 6; kx++) {
                const int kk = 6 * half + kx;
                #pragma unroll
                for (int mf = 0; mf < 2; mf++) {
                    const int row  = 16 * mf + cl;
                    const int boff = (kk * 64 + g * 16) ^ ((row & 7) << 4);
                    bf16x8 afh = *(const bf16x8*)(&lds[row * 768 + boff]);
                    bf16x8 afl = *(const bf16x8*)(&lds[24576 + row * 768 + boff]);
                    #pragma unroll
                    for (int t = 0; t < 3; t++) {
                        acc[mf][t] = __builtin_amdgcn_mfma_f32_16x16x32_bf16(afh, B[kx][t], acc[mf][t], 0, 0, 0);
                        acc[mf][t] = __builtin_amdgcn_mfma_f32_16x16x32_bf16(afl, B[kx][t], acc[mf][t], 0, 0, 0);
                    }
                }
            }
        }
    } else {
        #pragma unroll
        for (int kk = 0; kk < 12; kk++) {
            bf16x8 bh[3];
            #pragma unroll
            for (int t = 0; t < 3; t++) {
                const int n = (3 * wv + t) * 16 + cl;
                const float* wp = Wf + n * 384 + kk * 32 + g * 8;
                f32x4 lo = *(const f32x4*)wp;
                f32x4 hi4 = *(const f32x4*)(wp + 4);
                bf16x8 hbb;
                #pragma unroll
                for (int e = 0; e < 4; e++) {
                    hbb[e] = (short)f2bf(lo[e]); hbb[4 + e] = (short)f2bf(hi4[e]);
                }
                bh[t] = hbb;
            }
            #pragma unroll
            for (int mf = 0; mf < 2; mf++) {
                const int row  = 16 * mf + cl;
                const int boff = (kk * 64 + g * 16) ^ ((row & 7) << 4);
                bf16x8 afh = *(const bf16x8*)(&lds[row * 768 + boff]);
                bf16x8 afl = *(const bf16x8*)(&lds[24576 + row * 768 + boff]);
                #pragma unroll
                for (int t = 0; t < 3; t++) {
                    acc[mf][t] = __builtin_amdgcn_mfma_f32_16x16x32_bf16(afh, bh[t], acc[mf][t], 0, 0, 0);
                    acc[mf][t] = __builtin_amdgcn_mfma_f32_16x16x32_bf16(afl, bh[t], acc[mf][t], 0, 0, 0);
                }
            }
        }
    }
    __syncthreads();   // all A-reads done; reuse LDS for xs

    // ---------------- xs -> LDS f32 [32][196] ----------------
    {
        float* xsl = (float*)lds;
        #pragma unroll
        for (int mf = 0; mf < 2; mf++)
            #pragma unroll
            for (int t = 0; t < 3; t++) {
                const int col = 48 * wv + 16 * t + cl;   // D: col=lane&15, row=4*(lane>>4)+reg
                #pragma unroll
                for (int rg = 0; rg < 4; rg++) {
                    const int row = 16 * mf + 4 * g + rg;
                    xsl[row * 196 + col] = acc[mf][t][rg];
                }
            }
    }
    __syncthreads();

    // ---------------- epilogue: xv = xs + LN(xs); xa = LN(xv); out = LN(xa) ----------------
    {
        const float* rowp = (const float*)lds + r * 196 + u * 24;
        float vv[24];
        #pragma unroll
        for (int i = 0; i < 6; i++) {
            f32x4 t4 = *(const f32x4*)(rowp + 4 * i);
            #pragma unroll
            for (int e = 0; e < 4; e++) vv[4 * i + e] = t4[e];
        }
        float s1 = 0.f;
        #pragma unroll
        for (int i = 0; i < 24; i++) s1 += vv[i];
        s1 += __shfl_xor(s1, 1); s1 += __shfl_xor(s1, 2); s1 += __shfl_xor(s1, 4);
        const float mu1 = s1 * (1.f / 192.f);
        float d1 = 0.f;
        #pragma unroll
        for (int i = 0; i < 24; i++) { float d = vv[i] - mu1; d1 += d * d; }
        d1 += __shfl_xor(d1, 1); d1 += __shfl_xor(d1, 2); d1 += __shfl_xor(d1, 4);
        const float r1 = rsqrtf(d1 * (1.f / 192.f) + LN_EPS);

        const f32x4* vwv = (const f32x4*)(vw + u * 24);
        const f32x4* vbv = (const f32x4*)(vb + u * 24);
        float s2 = 0.f;
        #pragma unroll
        for (int i = 0; i < 6; i++) {
            f32x4 w4 = vwv[i], b4 = vbv[i];
            #pragma unroll
            for (int e = 0; e < 4; e++) {
                float xs0 = vv[4 * i + e];
                float xv0 = xs0 + (xs0 - mu1) * r1 * w4[e] + b4[e];
                vv[4 * i + e] = xv0;
                s2 += xv0;
            }
        }
        s2 += __shfl_xor(s2, 1); s2 += __shfl_xor(s2, 2); s2 += __shfl_xor(s2, 4);
        const float mu2 = s2 * (1.f / 192.f);
        float d2 = 0.f;
        #pragma unroll
        for (int i = 0; i < 24; i++) { float d = vv[i] - mu2; d2 += d * d; }
        d2 += __shfl_xor(d2, 1); d2 += __shfl_xor(d2, 2); d2 += __shfl_xor(d2, 4);
        const float r2 = rsqrtf(d2 * (1.f / 192.f) + LN_EPS);

        const f32x4* awv = (const f32x4*)(aw + u * 24);
        const f32x4* abv = (const f32x4*)(ab + u * 24);
        float s3 = 0.f;
        #pragma unroll
        for (int i = 0; i < 6; i++) {
            f32x4 w4 = awv[i], b4 = abv[i];
            #pragma unroll
            for (int e = 0; e < 4; e++) {
                float xa0 = (vv[4 * i + e] - mu2) * r2 * w4[e] + b4[e];
                vv[4 * i + e] = xa0;
                s3 += xa0;
            }
        }
        s3 += __shfl_xor(s3, 1); s3 += __shfl_xor(s3, 2); s3 += __shfl_xor(s3, 4);
        const float mu3 = s3 * (1.f / 192.f);
        float d3 = 0.f;
        #pragma unroll
        for (int i = 0; i < 24; i++) { float d = vv[i] - mu3; d3 += d * d; }
        d3 += __shfl_xor(d3, 1); d3 += __shfl_xor(d3, 2); d3 += __shfl_xor(d3, 4);
        const float r3 = rsqrtf(d3 * (1.f / 192.f) + LN_EPS);

        const f32x4* fwv = (const f32x4*)(fw + u * 24);
        const f32x4* fbv = (const f32x4*)(fb + u * 24);
        float* op = out + (size_t)(blockIdx.x * 32 + r) * 192 + u * 24;
        #pragma unroll
        for (int i = 0; i < 6; i++) {
            f32x4 w4 = fwv[i], b4 = fbv[i];
            f32x4 o4;
            #pragma unroll
            for (int e = 0; e < 4; e++)
                o4[e] = (vv[4 * i + e] - mu3) * r3 * w4[e] + b4[e];
            *(f32x4*)(op + 4 * i) = o4;
        }
    }
}

extern "C" void kernel_launch(void* const* d_in, const int* in_sizes, int n_in,
                              void* d_out, int out_size, void* d_ws, size_t ws_size,
                              hipStream_t stream) {
    const float* x  = (const float*)d_in[0];
    /* d_in[1] saliency_map: dead code in reference */
    const float* W  = (const float*)d_in[2];
    const float* mw = (const float*)d_in[3];
    const float* mb = (const float*)d_in[4];
    const float* vw = (const float*)d_in[5];
    const float* vb = (const float*)d_in[6];
    const float* aw = (const float*)d_in[7];
    const float* ab = (const float*)d_in[8];
    const float* fw = (const float*)d_in[9];
    const float* fb = (const float*)d_in[10];
    float* out = (float*)d_out;

    const int rows   = 8 * 112 * 112;     // 100352
    const int blocks = rows / 32;         // 3136

    unsigned short* wsh = (unsigned short*)d_ws;

    if (ws_size >= (size_t)(192 * 384 * 2)) {
        prep_w_kernel<<<288, 256, 0, stream>>>(W, wsh);
        fused_kernel<true><<<blocks, 256, 0, stream>>>(x, wsh, W, mw, mb, vw, vb,
                                                       aw, ab, fw, fb, out);
    } else {
        fused_kernel<false><<<blocks, 256, 0, stream>>>(x, wsh, W, mw, mb, vw, vb,
                                                        aw, ab, fw, fb, out);
    }
}